// Round 17
// baseline (687.399 us; speedup 1.0000x reference)
//
#include <hip/hip_runtime.h>

#define TT   64
#define NB   8
#define NN   512
#define HID  128
#define G4   512
#define EE   8192
#define SBLK 16
#define NTHR 1024
#define TCH  16
#define NCH  4

#define LOG2E 1.44269504088896f

// fast gates: v_exp2/v_rcp based, saturation-safe (rcp(inf)=0)
__device__ __forceinline__ float fsig(float x){
  return __builtin_amdgcn_rcpf(1.0f + __builtin_amdgcn_exp2f(-x*LOG2E));
}
__device__ __forceinline__ float ftanh(float x){
  return 1.0f - 2.0f*__builtin_amdgcn_rcpf(__builtin_amdgcn_exp2f(2.0f*LOG2E*x) + 1.0f);
}

using half8 = __attribute__((ext_vector_type(8))) _Float16;
using f32x4 = __attribute__((ext_vector_type(4))) float;

// pin a 4-VGPR value: compiler may not rematerialize/DCE it (R7/R14 remat guard)
__device__ __forceinline__ void keepv(half8& v){
  asm volatile("" : "+v"(*(f32x4*)&v));
}

// ---------------------------------------------------------------------------
// Weight prep (layout verified R5..R16): f32 [512][128] x5 -> fp16 planes in
// MFMA B-fragment order. Matrix m occupies 65536 fp16 (128KB):
//   [kt(4)][half(2)][nl(16)][lane(64)][8 fp16]
// lane l elem j <-> W[n=(half*16+nl)*16+(l&15)][k=kt*32+8*(l>>4)+j]
// mats: 0=whh0 1=wih1 2=whh1 3=wih2 4=whh2
// ---------------------------------------------------------------------------
__global__ void prep_w(const float* __restrict__ whh0, const float* __restrict__ wih1,
                       const float* __restrict__ whh1, const float* __restrict__ wih2,
                       const float* __restrict__ whh2, _Float16* __restrict__ wp)
{
  int idx = blockIdx.x*256 + threadIdx.x;      // 5*512*128 total
  int mat = idx >> 16;
  int r   = (idx >> 7) & 511;
  int k   = idx & 127;
  const float* src = (mat==0)?whh0:(mat==1)?wih1:(mat==2)?whh1:(mat==3)?wih2:whh2;
  float v = src[r*HID + k];
  int kt = k >> 5, kk = k & 31, s0 = kk >> 3, j = kk & 7;
  int nt = r >> 4, half = nt >> 4, nl = nt & 15;
  int l  = (r & 15) + 16*s0;
  wp[(mat*8 + kt*2 + half)*8192 + nl*512 + l*8 + j] = (_Float16)v;
}

// ---------------------------------------------------------------------------
// R17: K-split layer-phase. 16 waves: wave = (ug = wv&7, kh = wv>>3).
// Wave pins only its K-half's B-frags (whh 4x2 + wih 4x2 = 64 VGPR) ->
// 4 waves/SIMD at the 128-VGPR cap, 2x latency hiding vs R16.
// Step: MFMA K-half partials -> write exch -> B1 -> read other half, sum,
// cell for 2 seq-rows (rr = 2kh, 2kh+1) -> write hb/hseq -> B2.
// Hazards: exch w(preB1)/r(postB1)/overwrite(postB2); hb parity-disjoint;
// hseq[tt] read preB1 (input-proj) vs written postB1 (cell). All separated.
// ---------------------------------------------------------------------------
template<int L>
__device__ __forceinline__ void scan_phase(
    int ch, const _Float16* __restrict__ wp,
    const float* __restrict__ bihL, const float* __restrict__ bhhL,
    const float* __restrict__ wih0, _Float16* __restrict__ hsave,
    _Float16* hseq, _Float16* hb, float* exch, const _Float16* xall,
    float (&cs)[2], float* __restrict__ feats)
{
  const int tid  = threadIdx.x;
  const int lane = tid & 63, wv = tid >> 6, row = lane & 15;
  const int ug   = wv & 7, kh = wv >> 3;
  const int u    = 16*ug + row;
  const int blk  = blockIdx.x;
  const int s0b  = blk * SBLK;

  __syncthreads();                     // prev phase fully done (incl. hsave save)

  // ---- pinned B-fragments: 4 gate-tiles x 2 kt of this wave's K-half
  const char* whhG = (const char*)(wp + (L==0?0:(L==1?2:4))*65536);
  half8 Wf[4][2];
  #pragma unroll
  for (int g=0;g<4;g++)
    #pragma unroll
    for (int j=0;j<2;j++){
      int nt = g*8 + ug;
      Wf[g][j] = *(const half8*)(whhG + (2*kh+j)*32768 + (nt>>4)*16384
                                 + (nt&15)*1024 + lane*16);
      keepv(Wf[g][j]);
    }
  half8 Uf[4][2];
  if (L>0){
    const char* wihG = (const char*)(wp + (L==1?1:3)*65536);
    #pragma unroll
    for (int g=0;g<4;g++)
      #pragma unroll
      for (int j=0;j<2;j++){
        int nt = g*8 + ug;
        Uf[g][j] = *(const half8*)(wihG + (2*kh+j)*32768 + (nt>>4)*16384
                                   + (nt&15)*1024 + lane*16);
        keepv(Uf[g][j]);
      }
  }

  // ---- biases (+ L0 x-column)
  float bs[4], w0g[4];
  #pragma unroll
  for (int g=0;g<4;g++){
    bs[g] = bihL[g*HID+u] + bhhL[g*HID+u];
    w0g[g] = (L==0) ? wih0[g*HID+u] : 0.0f;
  }

  // ---- init recurrent h (buf0): zero (ch0) or restore (ch>0)
  if (ch == 0){
    for (int i=tid;i<2048;i+=NTHR) hb[i] = (_Float16)0.0f;
  } else {
    ((unsigned*)hb)[tid] =
      ((const unsigned*)(hsave + (size_t)(L*256+blk)*4096))[tid];  // 4KB
  }

  // ---- loop-invariant offsets
  int rboff[2];
  #pragma unroll
  for (int j=0;j<2;j++)
    rboff[j] = row*256 + ((((2*kh+j)<<6) + ((lane>>4)<<4)) ^ ((row&7)<<4));
  const int sqa = 4*(lane>>4) + 2*kh, sqb = sqa + 1;
  const int wbyA = sqa*256 + ((u*2) ^ ((sqa&7)<<4));
  const int wbyB = sqb*256 + ((u*2) ^ ((sqb&7)<<4));
  const int stA  = (ug>>1)*512 + (2*(ug&1)+(row>>3))*128 + sqa*8 + (lane&7);
  const int stB  = stA + 8;                    // sqb = sqa+1 -> +8 fp16
  int exWr[4], exRd[4];
  #pragma unroll
  for (int g=0;g<4;g++){
    exWr[g] = ((kh*32     + ug*4 + g)*64 + lane)*4;
    exRd[g] = (((1-kh)*32 + ug*4 + g)*64 + lane)*4;
  }

  __syncthreads();                     // hb init visible

  #pragma unroll 1
  for (int tt=0; tt<TCH; ++tt){
    const int t = ch*TCH + tt;

    // A-frags (K-half) + MFMA partials
    const char* hbR = (const char*)hb + (tt&1)*4096;
    half8 ahh0 = *(const half8*)(hbR + rboff[0]);
    half8 ahh1 = *(const half8*)(hbR + rboff[1]);
    f32x4 acc[4];
    #pragma unroll
    for (int g=0;g<4;g++) acc[g] = (f32x4){0.f,0.f,0.f,0.f};
    if (L>0){
      const char* hs = (const char*)hseq + tt*4096;
      half8 p0 = *(const half8*)(hs + (2*kh+0)*1024 + lane*16);
      half8 p1 = *(const half8*)(hs + (2*kh+1)*1024 + lane*16);
      #pragma unroll
      for (int g=0;g<4;g++){
        acc[g] = __builtin_amdgcn_mfma_f32_16x16x32_f16(p0, Uf[g][0], acc[g],0,0,0);
        acc[g] = __builtin_amdgcn_mfma_f32_16x16x32_f16(p1, Uf[g][1], acc[g],0,0,0);
      }
    }
    #pragma unroll
    for (int g=0;g<4;g++){
      acc[g] = __builtin_amdgcn_mfma_f32_16x16x32_f16(ahh0, Wf[g][0], acc[g],0,0,0);
      acc[g] = __builtin_amdgcn_mfma_f32_16x16x32_f16(ahh1, Wf[g][1], acc[g],0,0,0);
    }
    // publish partials
    #pragma unroll
    for (int g=0;g<4;g++) *(f32x4*)(exch + exWr[g]) = acc[g];

    __syncthreads();                   // B1: partials visible; hseq reads done

    // sum halves, pick this wave's 2 seq-rows (wave-uniform kh select)
    float ga[4], gb[4];
    #pragma unroll
    for (int g=0;g<4;g++){
      f32x4 og = *(const f32x4*)(exch + exRd[g]);
      float v0 = acc[g][0]+og[0], v1 = acc[g][1]+og[1];
      float v2 = acc[g][2]+og[2], v3 = acc[g][3]+og[3];
      ga[g] = bs[g] + (kh ? v2 : v0);
      gb[g] = bs[g] + (kh ? v3 : v1);
    }

    char* hbW = (char*)hb + ((tt+1)&1)*4096;
    _Float16* sq16 = hseq + tt*2048;
    // cell for rr0 = sqa
    {
      float iv=ga[0], fv=ga[1], gv=ga[2], ov=ga[3];
      if (L==0){ float xv = (float)xall[t*SBLK + sqa];
                 iv+=xv*w0g[0]; fv+=xv*w0g[1]; gv+=xv*w0g[2]; ov+=xv*w0g[3]; }
      float cn = fsig(fv)*cs[0] + fsig(iv)*ftanh(gv);
      cs[0]=cn; float hn = fsig(ov)*ftanh(cn);
      _Float16 hh = (_Float16)hn;
      *(_Float16*)(hbW + wbyA) = hh;
      if (L<2) sq16[stA] = hh;
      if (L==2 && t==TT-1) feats[(s0b + sqa)*HID + u] = hn;
    }
    // cell for rr1 = sqb
    {
      float iv=gb[0], fv=gb[1], gv=gb[2], ov=gb[3];
      if (L==0){ float xv = (float)xall[t*SBLK + sqb];
                 iv+=xv*w0g[0]; fv+=xv*w0g[1]; gv+=xv*w0g[2]; ov+=xv*w0g[3]; }
      float cn = fsig(fv)*cs[1] + fsig(iv)*ftanh(gv);
      cs[1]=cn; float hn = fsig(ov)*ftanh(cn);
      _Float16 hh = (_Float16)hn;
      *(_Float16*)(hbW + wbyB) = hh;
      if (L<2) sq16[stB] = hh;
      if (L==2 && t==TT-1) feats[(s0b + sqb)*HID + u] = hn;
    }

    __syncthreads();                   // B2: h(t) visible; exch reusable
  }

  if (ch < NCH-1){                     // save 4KB h-state (hb buf0) for next chunk
    ((unsigned*)(hsave + (size_t)(L*256+blk)*4096))[tid] = ((const unsigned*)hb)[tid];
  }
}

// ---------------------------------------------------------------------------
// Fused 3-layer LSTM scan, K-split 16-wave version.
// 256 blocks x 1024 thr (16 waves, 4/SIMD); 16 seqs/block; NCH=4 chunks of 16.
// LDS: 64K hseq + 64K exch + 8K hb(pp) + 2K xall = 138K.
// ---------------------------------------------------------------------------
__global__ __launch_bounds__(NTHR,1) void lstm_scan(
    const float* __restrict__ x,    const float* __restrict__ wih0,
    const float* __restrict__ bih0, const float* __restrict__ bhh0,
    const float* __restrict__ bih1, const float* __restrict__ bhh1,
    const float* __restrict__ bih2, const float* __restrict__ bhh2,
    const _Float16* __restrict__ wp, _Float16* __restrict__ hsave,
    float* __restrict__ feats)
{
  __shared__ __align__(16) _Float16 hseq[TCH*2048];  // 64 KB inter-layer h ring
  __shared__ __align__(16) float    exch[16384];     // 64 KB K-half partials
  __shared__ __align__(16) _Float16 hb[2*2048];      // 8 KB ping-pong h (fp16)
  __shared__ __align__(16) _Float16 xall[TT*SBLK];   // 2 KB

  const int tid = threadIdx.x;
  const int s0  = blockIdx.x * SBLK;
  const int b   = s0 >> 9, n0 = s0 & (NN-1);

  if (tid < TT*SBLK)
    xall[tid] = (_Float16)x[(b*TT + (tid>>4))*NN + n0 + (tid&15)];

  float cs0[2]={0,0}, cs1[2]={0,0}, cs2[2]={0,0};

  #pragma unroll 1
  for (int ch=0; ch<NCH; ++ch){
    scan_phase<0>(ch, wp, bih0, bhh0, wih0, hsave, hseq, hb, exch, xall, cs0, feats);
    scan_phase<1>(ch, wp, bih1, bhh1, wih0, hsave, hseq, hb, exch, xall, cs1, feats);
    scan_phase<2>(ch, wp, bih2, bhh2, wih0, hsave, hseq, hb, exch, xall, cs2, feats);
  }
}

// ---------------------------------------------------------------------------
// GCN part (unchanged from verified baseline)
// ---------------------------------------------------------------------------
template<int KOUT>
__global__ void gcn_gemm(const float* __restrict__ in, const float* __restrict__ W,
                         const float* __restrict__ pre_bias, float* __restrict__ out)
{
  int id  = blockIdx.x*256 + threadIdx.x;
  int row = id / KOUT;
  int o   = id & (KOUT-1);
  const float4* a4 = (const float4*)(in + row*HID);
  const float4* w4 = (const float4*)(W + o*HID);
  float acc = 0.f;
  if (pre_bias){
    const float4* b4 = (const float4*)pre_bias;
    #pragma unroll 8
    for (int k=0;k<HID/4;k++){
      float4 av=a4[k], wv=w4[k], bv=b4[k];
      acc += fmaxf(av.x+bv.x,0.f)*wv.x + fmaxf(av.y+bv.y,0.f)*wv.y
           + fmaxf(av.z+bv.z,0.f)*wv.z + fmaxf(av.w+bv.w,0.f)*wv.w;
    }
  } else {
    #pragma unroll 8
    for (int k=0;k<HID/4;k++){
      float4 av=a4[k], wv=w4[k];
      acc += av.x*wv.x + av.y*wv.y + av.z*wv.z + av.w*wv.w;
    }
  }
  out[id] = acc;
}

__global__ void deg_init(float* deg){
  int i = blockIdx.x*256 + threadIdx.x;
  if (i < NN) deg[i] = 1.0f;             // self-loop
}
__global__ void deg_edges(const int* __restrict__ ei, float* deg){
  int e = blockIdx.x*256 + threadIdx.x;
  if (e < EE) atomicAdd(&deg[ei[EE+e]], 1.0f);
}
__global__ void build_A(const int* __restrict__ ei, const float* __restrict__ deg,
                        float* __restrict__ A){
  int e = blockIdx.x*256 + threadIdx.x;
  if (e < EE){
    int s = ei[e], d = ei[EE+e];
    atomicAdd(&A[d*NN+s], rsqrtf(deg[s])*rsqrtf(deg[d]));
  } else if (e < EE+NN){
    int n = e - EE;
    atomicAdd(&A[n*NN+n], 1.0f/deg[n]);
  }
}

template<int KOUT>
__global__ __launch_bounds__(512) void gcn_agg(const float* __restrict__ A,
    const float* __restrict__ X, float* __restrict__ Y)
{
  const int F4 = KOUT/4;
  const int TN = 16;
  __shared__ __align__(16) float As[TN*NN];
  const int b = blockIdx.x, n0 = blockIdx.y*TN;
  const int tid = threadIdx.x;
  const int f4 = tid & (F4-1), nr = tid / F4;
  for (int i = tid; i < TN*NN; i += TN*F4) As[i] = A[n0*NN + i];
  __syncthreads();
  const float* Xb = X + b*NN*KOUT + f4*4;
  const float* Ar = As + nr*NN;
  float4 s = {0,0,0,0};
  #pragma unroll 4
  for (int m=0;m<NN;m++){
    float a = Ar[m];
    float4 xv = *(const float4*)(Xb + m*KOUT);
    s.x += a*xv.x; s.y += a*xv.y; s.z += a*xv.z; s.w += a*xv.w;
  }
  *(float4*)(Y + (b*NN + n0 + nr)*KOUT + f4*4) = s;
}

__global__ void finalize(const float* __restrict__ agg2, const float* __restrict__ b2,
                         const float* __restrict__ clw, const float* __restrict__ clb,
                         float* __restrict__ out)
{
  __shared__ float red[256];
  int bb = blockIdx.x, tid = threadIdx.x;
  float acc = 0.f;
  for (int i = tid; i < NN*64; i += 256){
    int j = i & 63;
    float v = agg2[bb*NN*64 + i] + b2[j];
    acc += fmaxf(v, 0.f) * clw[j];
  }
  red[tid] = acc; __syncthreads();
  for (int sfd=128; sfd>0; sfd>>=1){
    if (tid < sfd) red[tid] += red[tid+sfd];
    __syncthreads();
  }
  if (tid==0) out[bb] = red[0]*(1.0f/NN) + clb[0];
}

extern "C" void kernel_launch(void* const* d_in, const int* in_sizes, int n_in,
                              void* d_out, int out_size, void* d_ws, size_t ws_size,
                              hipStream_t stream)
{
  const float* x    = (const float*)d_in[0];
  const int*   ei   = (const int*)  d_in[1];
  const float* wih0 = (const float*)d_in[2];
  const float* whh0 = (const float*)d_in[3];
  const float* bih0 = (const float*)d_in[4];
  const float* bhh0 = (const float*)d_in[5];
  const float* wih1 = (const float*)d_in[6];
  const float* whh1 = (const float*)d_in[7];
  const float* bih1 = (const float*)d_in[8];
  const float* bhh1 = (const float*)d_in[9];
  const float* wih2 = (const float*)d_in[10];
  const float* whh2 = (const float*)d_in[11];
  const float* bih2 = (const float*)d_in[12];
  const float* bhh2 = (const float*)d_in[13];
  const float* g1w  = (const float*)d_in[14];
  const float* g1b  = (const float*)d_in[15];
  const float* g2w  = (const float*)d_in[16];
  const float* g2b  = (const float*)d_in[17];
  const float* clw  = (const float*)d_in[18];
  const float* clb  = (const float*)d_in[19];
  float* out = (float*)d_out;

  char* ws = (char*)d_ws;
  float* feats = (float*)(ws);                 // [4096,128]  2 MB
  float* xl1   = (float*)(ws + 2097152);       // [8,512,128] 2 MB (post-lstm)
  float* agg1  = (float*)(ws + 4194304);       // [8,512,128] 2 MB (post-lstm)
  float* xl2   = (float*)(ws + 6291456);       // [8,512,64]  1 MB (post-lstm)
  float* agg2  = (float*)(ws + 7340032);       // [8,512,64]  1 MB (post-lstm)
  float* A     = (float*)(ws + 8388608);       // [512,512]   1 MB
  float* deg   = (float*)(ws + 9437184);       // [512]

  // Overlays (safe by stream order + verified self-alias layout):
  //  - hsave [3][256] stride 8KB = 6MB at ws+0 (feats/xl1/agg1 dead during
  //    scan; block i's feats region == hsave[0][i], restored before written).
  //  - wp (640KB fp16 weight planes) in the xl2 slot.
  _Float16* hsaveW = (_Float16*)(ws);
  _Float16* wpW    = (_Float16*)(ws + 6291456);

  prep_w<<<(5*G4*HID)/256, 256, 0, stream>>>(whh0, wih1, whh1, wih2, whh2, wpW);

  hipMemsetAsync(A, 0, NN*NN*sizeof(float), stream);
  deg_init <<<2, 256, 0, stream>>>(deg);
  deg_edges<<<EE/256, 256, 0, stream>>>(ei, deg);
  build_A  <<<(EE+NN+255)/256, 256, 0, stream>>>(ei, deg, A);

  lstm_scan<<<256, NTHR, 0, stream>>>(x, wih0, bih0, bhh0,
      bih1, bhh1, bih2, bhh2, wpW, hsaveW, feats);

  gcn_gemm<128><<<(4096*128)/256, 256, 0, stream>>>(feats, g1w, nullptr, xl1);
  gcn_agg<128><<<dim3(NB, NN/16), 512, 0, stream>>>(A, xl1, agg1);
  gcn_gemm<64><<<(4096*64)/256, 256, 0, stream>>>(agg1, g2w, g1b, xl2);
  gcn_agg<64><<<dim3(NB, NN/16), 256, 0, stream>>>(A, xl2, agg2);
  finalize<<<NB, 256, 0, stream>>>(agg2, g2b, clw, clb, out);
}

// Round 18
// 540.779 us; speedup vs baseline: 1.2711x; 1.2711x over previous
//
#include <hip/hip_runtime.h>

#define TT   64
#define NB   8
#define NN   512
#define HID  128
#define G4   512
#define EE   8192
#define SBLK 16
#define NTHR 512
#define TCH  32
#define NCH  2

#define LOG2E 1.44269504088896f

// fast gates: v_exp2/v_rcp based, saturation-safe (rcp(inf)=0)
__device__ __forceinline__ float fsig(float x){
  return __builtin_amdgcn_rcpf(1.0f + __builtin_amdgcn_exp2f(-x*LOG2E));
}
__device__ __forceinline__ float ftanh(float x){
  return 1.0f - 2.0f*__builtin_amdgcn_rcpf(__builtin_amdgcn_exp2f(2.0f*LOG2E*x) + 1.0f);
}

using half8 = __attribute__((ext_vector_type(8))) _Float16;
using f32x4 = __attribute__((ext_vector_type(4))) float;

// pin a 4-VGPR value: compiler may not rematerialize/DCE it (R7/R14 remat guard)
__device__ __forceinline__ void keepv(half8& v){
  asm volatile("" : "+v"(*(f32x4*)&v));
}

// ---------------------------------------------------------------------------
// Weight prep (layout verified R5..R16): f32 [512][128] x5 -> fp16 planes in
// MFMA B-fragment order. Matrix m occupies 65536 fp16 (128KB):
//   [kt(4)][half(2)][nl(16)][lane(64)][8 fp16]
// lane l elem j <-> W[n=(half*16+nl)*16+(l&15)][k=kt*32+8*(l>>4)+j]
// mats: 0=whh0 1=wih1 2=whh1 3=wih2 4=whh2
// ---------------------------------------------------------------------------
__global__ void prep_w(const float* __restrict__ whh0, const float* __restrict__ wih1,
                       const float* __restrict__ whh1, const float* __restrict__ wih2,
                       const float* __restrict__ whh2, _Float16* __restrict__ wp)
{
  int idx = blockIdx.x*256 + threadIdx.x;      // 5*512*128 total
  int mat = idx >> 16;
  int r   = (idx >> 7) & 511;
  int k   = idx & 127;
  const float* src = (mat==0)?whh0:(mat==1)?wih1:(mat==2)?whh1:(mat==3)?wih2:whh2;
  float v = src[r*HID + k];
  int kt = k >> 5, kk = k & 31, s0 = kk >> 3, j = kk & 7;
  int nt = r >> 4, half = nt >> 4, nl = nt & 15;
  int l  = (r & 15) + 16*s0;
  wp[(mat*8 + kt*2 + half)*8192 + nl*512 + l*8 + j] = (_Float16)v;
}

// ---------------------------------------------------------------------------
// One layer-phase over [ch*TCH, ch*TCH+TCH). R16-verified structure:
// SINGLE-fp16 recurrent h; whh/wih B-fragments global -> pinned regs once
// per phase; inter-layer h in LDS hseq ring; ping-pong hb; 1 barrier/step;
// zero global memory ops in the steady-state loop.
// ---------------------------------------------------------------------------
template<int L>
__device__ __forceinline__ void scan_phase(
    int ch, const _Float16* __restrict__ wp, _Float16* __restrict__ hsave,
    _Float16* hseq, _Float16* hb, const _Float16* xall,
    float4 bL, float4 w0g, float (&cs)[4], float (&hlast)[4])
{
  const int tid  = threadIdx.x;
  const int lane = tid & 63, wv = tid >> 6, row = lane & 15;
  const int u    = 16*wv + row;
  const int blk  = blockIdx.x;

  __syncthreads();                     // phase entry: prev phase's hseq/hb done

  // ---- whh B-fragments: global -> pinned regs (L2-hot 640KB pool)
  const char* whhG = (const char*)(wp + (L==0?0:(L==1?2:4))*65536);
  half8 Wf[4][4];
  #pragma unroll
  for (int g=0;g<4;g++)
    #pragma unroll
    for (int kt=0;kt<4;kt++){
      Wf[g][kt] = *(const half8*)(whhG + kt*32768 + (g>>1)*16384
                                  + (wv+8*(g&1))*1024 + lane*16);
      keepv(Wf[g][kt]);
    }
  // ---- wih B-fragments (L>0): global -> pinned regs
  half8 wih[4][4];
  if (L>0){
    const char* wihG = (const char*)(wp + (L==1?1:3)*65536);
    #pragma unroll
    for (int g=0;g<4;g++)
      #pragma unroll
      for (int kt=0;kt<4;kt++){
        wih[g][kt] = *(const half8*)(wihG + kt*32768 + (g>>1)*16384
                                     + (wv+8*(g&1))*1024 + lane*16);
        keepv(wih[g][kt]);
      }
  }

  // ---- init recurrent h-state (buf0, 4KB): zero (ch0) or restore (ch1)
  if (ch == 0){
    for (int i=tid;i<2048;i+=NTHR) hb[i] = (_Float16)0.0f;
  } else {
    const unsigned long long* s =
      (const unsigned long long*)(hsave + (size_t)(L*256+blk)*4096);
    ((unsigned long long*)hb)[tid] = s[tid];                      // 4KB restore
  }

  // ---- loop-invariant offsets
  int rboff[4], wbyteW[4], stoffW[4];
  #pragma unroll
  for (int kt=0;kt<4;kt++)
    rboff[kt] = row*256 + (((kt<<6) + ((lane>>4)<<4)) ^ ((row&7)<<4));
  #pragma unroll
  for (int r=0;r<4;r++){
    int sq = 4*(lane>>4)+r;
    wbyteW[r] = sq*256 + ((u*2) ^ ((sq&7)<<4));
    stoffW[r] = (wv>>1)*512 + (2*(wv&1)+((lane&15)>>3))*128 + sq*8 + (lane&7);
  }

  __syncthreads();                     // hb init visible

  const char* hseq_c = (const char*)hseq;
  half8 pfA[4];
  if (L>0){                            // prefetch tile 0 (prev-layer h)
    #pragma unroll
    for (int kt=0;kt<4;kt++)
      pfA[kt] = *(const half8*)(hseq_c + kt*1024 + lane*16);
  }

  #pragma unroll 1
  for (int tt=0; tt<TCH; ++tt){
    const int t = ch*TCH + tt;
    __syncthreads();                   // single barrier per step (lgkm-only)

    f32x4 acc[4];
    #pragma unroll
    for (int g=0;g<4;g++) acc[g] = (f32x4){bL[g],bL[g],bL[g],bL[g]};

    if (L>0){                          // input-projection term (prev-layer h)
      #pragma unroll
      for (int g=0;g<4;g++)
        #pragma unroll
        for (int kt=0;kt<4;kt++)
          acc[g] = __builtin_amdgcn_mfma_f32_16x16x32_f16(pfA[kt], wih[g][kt], acc[g],0,0,0);
    }

    // recurrent term: A = h(t-1) fp16 from hb[tt&1], B = whh (pinned regs)
    const char* hbR = (const char*)hb + (tt&1)*4096;
    half8 ahh[4];
    #pragma unroll
    for (int kt=0;kt<4;kt++)
      ahh[kt] = *(const half8*)(hbR + rboff[kt]);
    #pragma unroll
    for (int g=0;g<4;g++)
      #pragma unroll
      for (int kt=0;kt<4;kt++)
        acc[g] = __builtin_amdgcn_mfma_f32_16x16x32_f16(ahh[kt], Wf[g][kt], acc[g],0,0,0);

    if (L>0 && tt+1 < TCH){            // prefetch hseq[tt+1] (safe: its next
      #pragma unroll                   // writer runs after the NEXT barrier)
      for (int kt=0;kt<4;kt++)
        pfA[kt] = *(const half8*)(hseq_c + (tt+1)*4096 + kt*1024 + lane*16);
    }

    char* hbW = (char*)hb + ((tt+1)&1)*4096;
    _Float16* sq16 = hseq + tt*2048;   // this step's hseq tile (overwrite ok:
    #pragma unroll                     // all pfA[tt] reads were pre-barrier)
    for (int r=0;r<4;r++){
      float iv=acc[0][r], fv=acc[1][r], gv=acc[2][r], ov=acc[3][r];
      if (L==0){
        float xv = (float)xall[t*SBLK + 4*(lane>>4)+r];
        iv+=xv*w0g[0]; fv+=xv*w0g[1]; gv+=xv*w0g[2]; ov+=xv*w0g[3];
      }
      float cn = fsig(fv)*cs[r] + fsig(iv)*ftanh(gv);
      cs[r]=cn; float hn = fsig(ov)*ftanh(cn);
      _Float16 hh = (_Float16)hn;
      *(_Float16*)(hbW + wbyteW[r]) = hh;
      if (L<2) sq16[stoffW[r]] = hh;   // fragment-ordered hseq write
      if (L==2 && t==TT-1) hlast[r]=hn;
    }
  }

  __syncthreads();                     // final writes visible
  if (NCH>1 && ch==0){                 // save 4KB h-state for next chunk
    // hsave entry STRIDE stays 8KB (R13 layout): feats/hsave overlay is
    // then self-block-aliased only (block i's feats region == hsave[0][i]).
    unsigned long long* d =
      (unsigned long long*)(hsave + (size_t)(L*256+blk)*4096);
    d[tid] = ((const unsigned long long*)((const char*)hb + (TCH&1)*4096))[tid];
  }
}

// ---------------------------------------------------------------------------
// Fused 3-layer LSTM scan: layer-sequential, weights in pinned regs,
// inter-layer h in LDS hseq ring, single-fp16 h, 1 barrier/step.
// 256 blocks x 512 thr; 16 seqs/block x 3 layers x 64 steps (2 chunks of 32).
// LDS: 128K hseq + 8K hb(pp) + 2K xall = 138K.  (R16-verified: 332us)
// ---------------------------------------------------------------------------
__global__ __launch_bounds__(NTHR,2) void lstm_scan(
    const float* __restrict__ x,    const float* __restrict__ wih0,
    const float* __restrict__ bih0, const float* __restrict__ bhh0,
    const float* __restrict__ bih1, const float* __restrict__ bhh1,
    const float* __restrict__ bih2, const float* __restrict__ bhh2,
    const _Float16* __restrict__ wp, _Float16* __restrict__ hsave,
    float* __restrict__ feats)
{
  __shared__ __align__(16) _Float16 hseq[TCH*2048];  // 128 KB inter-layer h ring
  __shared__ __align__(16) _Float16 hb[2*2048];      // 8 KB ping-pong h (fp16)
  __shared__ __align__(16) _Float16 xall[TT*SBLK];   // 2 KB

  const int tid  = threadIdx.x;
  const int lane = tid & 63, wv = tid >> 6;
  const int u    = 16*wv + (lane & 15);
  const int s0   = blockIdx.x * SBLK;
  const int b    = s0 >> 9, n0 = s0 & (NN-1);

  for (int i = tid; i < TT*SBLK; i += NTHR)
    xall[i] = (_Float16)x[(b*TT + (i>>4))*NN + n0 + (i&15)];

  float4 b0, b1, b2, w0g;
  #pragma unroll
  for (int g=0; g<4; g++){
    b0[g]  = bih0[g*HID+u] + bhh0[g*HID+u];
    b1[g]  = bih1[g*HID+u] + bhh1[g*HID+u];
    b2[g]  = bih2[g*HID+u] + bhh2[g*HID+u];
    w0g[g] = wih0[g*HID+u];
  }

  float cs0[4]={0,0,0,0}, cs1[4]={0,0,0,0}, cs2[4]={0,0,0,0};
  float hlast[4]={0,0,0,0};

  #pragma unroll 1
  for (int ch=0; ch<NCH; ++ch){
    scan_phase<0>(ch, wp, hsave, hseq, hb, xall, b0, w0g, cs0, hlast);
    scan_phase<1>(ch, wp, hsave, hseq, hb, xall, b1, w0g, cs1, hlast);
    scan_phase<2>(ch, wp, hsave, hseq, hb, xall, b2, w0g, cs2, hlast);
  }

  #pragma unroll
  for (int r=0;r<4;r++)
    feats[(s0 + 4*(lane>>4) + r)*HID + u] = hlast[r];
}

// ---------------------------------------------------------------------------
// GCN part
// ---------------------------------------------------------------------------
template<int KOUT>
__global__ void gcn_gemm(const float* __restrict__ in, const float* __restrict__ W,
                         const float* __restrict__ pre_bias, float* __restrict__ out)
{
  int id  = blockIdx.x*256 + threadIdx.x;
  int row = id / KOUT;
  int o   = id & (KOUT-1);
  const float4* a4 = (const float4*)(in + row*HID);
  const float4* w4 = (const float4*)(W + o*HID);
  float acc = 0.f;
  if (pre_bias){
    const float4* b4 = (const float4*)pre_bias;
    #pragma unroll 8
    for (int k=0;k<HID/4;k++){
      float4 av=a4[k], wv=w4[k], bv=b4[k];
      acc += fmaxf(av.x+bv.x,0.f)*wv.x + fmaxf(av.y+bv.y,0.f)*wv.y
           + fmaxf(av.z+bv.z,0.f)*wv.z + fmaxf(av.w+bv.w,0.f)*wv.w;
    }
  } else {
    #pragma unroll 8
    for (int k=0;k<HID/4;k++){
      float4 av=a4[k], wv=w4[k];
      acc += av.x*wv.x + av.y*wv.y + av.z*wv.z + av.w*wv.w;
    }
  }
  out[id] = acc;
}

__global__ void deg_init(float* deg, float* out, const float* __restrict__ clb){
  int i = blockIdx.x*256 + threadIdx.x;
  if (i < NN) deg[i] = 1.0f;             // self-loop
  if (i < NB) out[i] = clb[0];           // seed classifier bias (atomics add)
}
__global__ void deg_edges(const int* __restrict__ ei, float* deg){
  int e = blockIdx.x*256 + threadIdx.x;
  if (e < EE) atomicAdd(&deg[ei[EE+e]], 1.0f);
}
__global__ void build_A(const int* __restrict__ ei, const float* __restrict__ deg,
                        float* __restrict__ A){
  int e = blockIdx.x*256 + threadIdx.x;
  if (e < EE){
    int s = ei[e], d = ei[EE+e];
    atomicAdd(&A[d*NN+s], rsqrtf(deg[s])*rsqrtf(deg[d]));
  } else if (e < EE+NN){
    int n = e - EE;
    atomicAdd(&A[n*NN+n], 1.0f/deg[n]);
  }
}

template<int KOUT>
__global__ __launch_bounds__(512) void gcn_agg(const float* __restrict__ A,
    const float* __restrict__ X, float* __restrict__ Y)
{
  const int F4 = KOUT/4;
  const int TN = 16;
  __shared__ __align__(16) float As[TN*NN];
  const int b = blockIdx.x, n0 = blockIdx.y*TN;
  const int tid = threadIdx.x;
  const int f4 = tid & (F4-1), nr = tid / F4;
  for (int i = tid; i < TN*NN; i += TN*F4) As[i] = A[n0*NN + i];
  __syncthreads();
  const float* Xb = X + b*NN*KOUT + f4*4;
  const float* Ar = As + nr*NN;
  float4 s = {0,0,0,0};
  #pragma unroll 4
  for (int m=0;m<NN;m++){
    float a = Ar[m];
    float4 xv = *(const float4*)(Xb + m*KOUT);
    s.x += a*xv.x; s.y += a*xv.y; s.z += a*xv.z; s.w += a*xv.w;
  }
  *(float4*)(Y + (b*NN + n0 + nr)*KOUT + f4*4) = s;
}

// agg2 + finalize fused: Y2 never materialized. Each block computes its
// 16 rows x 64 feats of A@X2, applies relu(y+b2).clw, block-reduces, and
// atomicAdds the 1/NN-scaled partial into out[b] (out pre-seeded with clb).
__global__ __launch_bounds__(256) void gcn_agg_fin(const float* __restrict__ A,
    const float* __restrict__ X, const float* __restrict__ b2,
    const float* __restrict__ clw, float* __restrict__ out)
{
  const int KOUT = 64, F4 = 16, TN = 16;
  __shared__ __align__(16) float As[TN*NN];
  __shared__ float red[256];
  const int b = blockIdx.x, n0 = blockIdx.y*TN;
  const int tid = threadIdx.x;
  const int f4 = tid & (F4-1), nr = tid / F4;
  for (int i = tid; i < TN*NN; i += TN*F4) As[i] = A[n0*NN + i];
  __syncthreads();
  const float* Xb = X + b*NN*KOUT + f4*4;
  const float* Ar = As + nr*NN;
  float4 s = {0,0,0,0};
  #pragma unroll 4
  for (int m=0;m<NN;m++){
    float a = Ar[m];
    float4 xv = *(const float4*)(Xb + m*KOUT);
    s.x += a*xv.x; s.y += a*xv.y; s.z += a*xv.z; s.w += a*xv.w;
  }
  const float4 bv = *(const float4*)(b2 + f4*4);
  const float4 cv = *(const float4*)(clw + f4*4);
  float p = fmaxf(s.x+bv.x,0.f)*cv.x + fmaxf(s.y+bv.y,0.f)*cv.y
          + fmaxf(s.z+bv.z,0.f)*cv.z + fmaxf(s.w+bv.w,0.f)*cv.w;
  red[tid] = p; __syncthreads();
  for (int sfd=128; sfd>0; sfd>>=1){
    if (tid < sfd) red[tid] += red[tid+sfd];
    __syncthreads();
  }
  if (tid==0) atomicAdd(&out[b], red[0]*(1.0f/NN));
}

extern "C" void kernel_launch(void* const* d_in, const int* in_sizes, int n_in,
                              void* d_out, int out_size, void* d_ws, size_t ws_size,
                              hipStream_t stream)
{
  const float* x    = (const float*)d_in[0];
  const int*   ei   = (const int*)  d_in[1];
  const float* wih0 = (const float*)d_in[2];
  const float* whh0 = (const float*)d_in[3];
  const float* bih0 = (const float*)d_in[4];
  const float* bhh0 = (const float*)d_in[5];
  const float* wih1 = (const float*)d_in[6];
  const float* whh1 = (const float*)d_in[7];
  const float* bih1 = (const float*)d_in[8];
  const float* bhh1 = (const float*)d_in[9];
  const float* wih2 = (const float*)d_in[10];
  const float* whh2 = (const float*)d_in[11];
  const float* bih2 = (const float*)d_in[12];
  const float* bhh2 = (const float*)d_in[13];
  const float* g1w  = (const float*)d_in[14];
  const float* g1b  = (const float*)d_in[15];
  const float* g2w  = (const float*)d_in[16];
  const float* g2b  = (const float*)d_in[17];
  const float* clw  = (const float*)d_in[18];
  const float* clb  = (const float*)d_in[19];
  float* out = (float*)d_out;

  char* ws = (char*)d_ws;
  float* feats = (float*)(ws);                 // [4096,128]  2 MB
  float* xl1   = (float*)(ws + 2097152);       // [8,512,128] 2 MB (post-lstm)
  float* agg1  = (float*)(ws + 4194304);       // [8,512,128] 2 MB (post-lstm)
  float* xl2   = (float*)(ws + 6291456);       // [8,512,64]  1 MB (post-lstm)
  float* A     = (float*)(ws + 8388608);       // [512,512]   1 MB
  float* deg   = (float*)(ws + 9437184);       // [512]

  // Overlays (safe by stream order + R13/R16-verified self-alias layout):
  //  - hsave [3][256] stride 8KB = 6MB at ws+0 (feats/xl1/agg1 dead during
  //    scan; block i's feats region == hsave[0][i], restored before written).
  //  - wp (640KB fp16 weight planes) in the xl2 slot.
  _Float16* hsaveW = (_Float16*)(ws);
  _Float16* wpW    = (_Float16*)(ws + 6291456);

  prep_w<<<(5*G4*HID)/256, 256, 0, stream>>>(whh0, wih1, whh1, wih2, whh2, wpW);

  hipMemsetAsync(A, 0, NN*NN*sizeof(float), stream);
  deg_init <<<2, 256, 0, stream>>>(deg, out, clb);
  deg_edges<<<EE/256, 256, 0, stream>>>(ei, deg);
  build_A  <<<(EE+NN+255)/256, 256, 0, stream>>>(ei, deg, A);

  lstm_scan<<<256, NTHR, 0, stream>>>(x, wih0, bih0, bhh0,
      bih1, bhh1, bih2, bhh2, wpW, hsaveW, feats);

  gcn_gemm<128><<<(4096*128)/256, 256, 0, stream>>>(feats, g1w, nullptr, xl1);
  gcn_agg<128><<<dim3(NB, NN/16), 512, 0, stream>>>(A, xl1, agg1);
  gcn_gemm<64><<<(4096*64)/256, 256, 0, stream>>>(agg1, g2w, g1b, xl2);
  gcn_agg_fin<<<dim3(NB, NN/16), 256, 0, stream>>>(A, xl2, g2b, clw, out);
}

// Round 20
// 513.283 us; speedup vs baseline: 1.3392x; 1.0536x over previous
//
#include <hip/hip_runtime.h>

#define TT   64
#define NB   8
#define NN   512
#define HID  128
#define G4   512
#define EE   8192
#define SBLK 16
#define NTHR 512
#define TCH  32
#define NCH  2

#define LOG2E 1.44269504088896f

// fast gates: v_exp2/v_rcp based, saturation-safe (rcp(inf)=0)
__device__ __forceinline__ float fsig(float x){
  return __builtin_amdgcn_rcpf(1.0f + __builtin_amdgcn_exp2f(-x*LOG2E));
}
__device__ __forceinline__ float ftanh(float x){
  return 1.0f - 2.0f*__builtin_amdgcn_rcpf(__builtin_amdgcn_exp2f(2.0f*LOG2E*x) + 1.0f);
}

using half8 = __attribute__((ext_vector_type(8))) _Float16;
using f32x4 = __attribute__((ext_vector_type(4))) float;

// pin a 4-VGPR value: compiler may not rematerialize/DCE it (R7/R14 remat guard)
__device__ __forceinline__ void keepv(half8& v){
  asm volatile("" : "+v"(*(f32x4*)&v));
}

// ---------------------------------------------------------------------------
// Weight prep (layout verified R5..R18): f32 [512][128] x5 -> fp16 planes in
// MFMA B-fragment order. Matrix m occupies 65536 fp16 (128KB):
//   [kt(4)][half(2)][nl(16)][lane(64)][8 fp16]
// lane l elem j <-> W[n=(half*16+nl)*16+(l&15)][k=kt*32+8*(l>>4)+j]
// mats: 0=whh0 1=wih1 2=whh1 3=wih2 4=whh2
// ---------------------------------------------------------------------------
__global__ void prep_w(const float* __restrict__ whh0, const float* __restrict__ wih1,
                       const float* __restrict__ whh1, const float* __restrict__ wih2,
                       const float* __restrict__ whh2, _Float16* __restrict__ wp)
{
  int idx = blockIdx.x*256 + threadIdx.x;      // 5*512*128 total
  int mat = idx >> 16;
  int r   = (idx >> 7) & 511;
  int k   = idx & 127;
  const float* src = (mat==0)?whh0:(mat==1)?wih1:(mat==2)?whh1:(mat==3)?wih2:whh2;
  float v = src[r*HID + k];
  int kt = k >> 5, kk = k & 31, s0 = kk >> 3, j = kk & 7;
  int nt = r >> 4, half = nt >> 4, nl = nt & 15;
  int l  = (r & 15) + 16*s0;
  wp[(mat*8 + kt*2 + half)*8192 + nl*512 + l*8 + j] = (_Float16)v;
}

// ---------------------------------------------------------------------------
// One layer-phase over [ch*TCH, ch*TCH+TCH). R16-verified structure:
// SINGLE-fp16 recurrent h; whh/wih B-fragments global -> pinned regs once
// per phase; inter-layer h in LDS hseq ring; ping-pong hb; 1 barrier/step;
// zero global memory ops in the steady-state loop.
// ---------------------------------------------------------------------------
template<int L>
__device__ __forceinline__ void scan_phase(
    int ch, const _Float16* __restrict__ wp, _Float16* __restrict__ hsave,
    _Float16* hseq, _Float16* hb, const _Float16* xall,
    float4 bL, float4 w0g, float (&cs)[4], float (&hlast)[4])
{
  const int tid  = threadIdx.x;
  const int lane = tid & 63, wv = tid >> 6, row = lane & 15;
  const int u    = 16*wv + row;
  const int blk  = blockIdx.x;

  __syncthreads();                     // phase entry: prev phase's hseq/hb done

  // ---- whh B-fragments: global -> pinned regs (L2-hot 640KB pool)
  const char* whhG = (const char*)(wp + (L==0?0:(L==1?2:4))*65536);
  half8 Wf[4][4];
  #pragma unroll
  for (int g=0;g<4;g++)
    #pragma unroll
    for (int kt=0;kt<4;kt++){
      Wf[g][kt] = *(const half8*)(whhG + kt*32768 + (g>>1)*16384
                                  + (wv+8*(g&1))*1024 + lane*16);
      keepv(Wf[g][kt]);
    }
  // ---- wih B-fragments (L>0): global -> pinned regs
  half8 wih[4][4];
  if (L>0){
    const char* wihG = (const char*)(wp + (L==1?1:3)*65536);
    #pragma unroll
    for (int g=0;g<4;g++)
      #pragma unroll
      for (int kt=0;kt<4;kt++){
        wih[g][kt] = *(const half8*)(wihG + kt*32768 + (g>>1)*16384
                                     + (wv+8*(g&1))*1024 + lane*16);
        keepv(wih[g][kt]);
      }
  }

  // ---- init recurrent h-state (buf0, 4KB): zero (ch0) or restore (ch1)
  if (ch == 0){
    for (int i=tid;i<2048;i+=NTHR) hb[i] = (_Float16)0.0f;
  } else {
    const unsigned long long* s =
      (const unsigned long long*)(hsave + (size_t)(L*256+blk)*4096);
    ((unsigned long long*)hb)[tid] = s[tid];                      // 4KB restore
  }

  // ---- loop-invariant offsets
  int rboff[4], wbyteW[4], stoffW[4];
  #pragma unroll
  for (int kt=0;kt<4;kt++)
    rboff[kt] = row*256 + (((kt<<6) + ((lane>>4)<<4)) ^ ((row&7)<<4));
  #pragma unroll
  for (int r=0;r<4;r++){
    int sq = 4*(lane>>4)+r;
    wbyteW[r] = sq*256 + ((u*2) ^ ((sq&7)<<4));
    stoffW[r] = (wv>>1)*512 + (2*(wv&1)+((lane&15)>>3))*128 + sq*8 + (lane&7);
  }

  __syncthreads();                     // hb init visible

  const char* hseq_c = (const char*)hseq;
  half8 pfA[4];
  if (L>0){                            // prefetch tile 0 (prev-layer h)
    #pragma unroll
    for (int kt=0;kt<4;kt++)
      pfA[kt] = *(const half8*)(hseq_c + kt*1024 + lane*16);
  }

  #pragma unroll 1
  for (int tt=0; tt<TCH; ++tt){
    const int t = ch*TCH + tt;
    __syncthreads();                   // single barrier per step (lgkm-only)

    f32x4 acc[4];
    #pragma unroll
    for (int g=0;g<4;g++) acc[g] = (f32x4){bL[g],bL[g],bL[g],bL[g]};

    if (L>0){                          // input-projection term (prev-layer h)
      #pragma unroll
      for (int g=0;g<4;g++)
        #pragma unroll
        for (int kt=0;kt<4;kt++)
          acc[g] = __builtin_amdgcn_mfma_f32_16x16x32_f16(pfA[kt], wih[g][kt], acc[g],0,0,0);
    }

    // recurrent term: A = h(t-1) fp16 from hb[tt&1], B = whh (pinned regs)
    const char* hbR = (const char*)hb + (tt&1)*4096;
    half8 ahh[4];
    #pragma unroll
    for (int kt=0;kt<4;kt++)
      ahh[kt] = *(const half8*)(hbR + rboff[kt]);
    #pragma unroll
    for (int g=0;g<4;g++)
      #pragma unroll
      for (int kt=0;kt<4;kt++)
        acc[g] = __builtin_amdgcn_mfma_f32_16x16x32_f16(ahh[kt], Wf[g][kt], acc[g],0,0,0);

    if (L>0 && tt+1 < TCH){            // prefetch hseq[tt+1] (safe: its next
      #pragma unroll                   // writer runs after the NEXT barrier)
      for (int kt=0;kt<4;kt++)
        pfA[kt] = *(const half8*)(hseq_c + (tt+1)*4096 + kt*1024 + lane*16);
    }

    char* hbW = (char*)hb + ((tt+1)&1)*4096;
    _Float16* sq16 = hseq + tt*2048;   // this step's hseq tile (overwrite ok:
    #pragma unroll                     // all pfA[tt] reads were pre-barrier)
    for (int r=0;r<4;r++){
      float iv=acc[0][r], fv=acc[1][r], gv=acc[2][r], ov=acc[3][r];
      if (L==0){
        float xv = (float)xall[t*SBLK + 4*(lane>>4)+r];
        iv+=xv*w0g[0]; fv+=xv*w0g[1]; gv+=xv*w0g[2]; ov+=xv*w0g[3];
      }
      float cn = fsig(fv)*cs[r] + fsig(iv)*ftanh(gv);
      cs[r]=cn; float hn = fsig(ov)*ftanh(cn);
      _Float16 hh = (_Float16)hn;
      *(_Float16*)(hbW + wbyteW[r]) = hh;
      if (L<2) sq16[stoffW[r]] = hh;   // fragment-ordered hseq write
      if (L==2 && t==TT-1) hlast[r]=hn;
    }
  }

  __syncthreads();                     // final writes visible
  if (NCH>1 && ch==0){                 // save 4KB h-state for next chunk
    // hsave entry STRIDE stays 8KB: feats/xl1/hsave overlays are then
    // self-block-aliased only (block i touches only its own entries).
    unsigned long long* d =
      (unsigned long long*)(hsave + (size_t)(L*256+blk)*4096);
    d[tid] = ((const unsigned long long*)((const char*)hb + (TCH&1)*4096))[tid];
  }
}

// ---------------------------------------------------------------------------
// Fused 3-layer LSTM scan + first GCN GEMM (xl1 = h_last @ g1w^T).
// 256 blocks x 512 thr; 16 seqs/block x 3 layers x 64 steps (2 chunks of 32).
// LDS: 128K hseq + 8K hb(pp) + 2K xall = 138K.  (scan R16-verified: 332us)
// Epilogue: h_last tile (16x128 fp32) -> hb LDS, then 4 dot-128s per thread.
// ---------------------------------------------------------------------------
__global__ __launch_bounds__(NTHR,2) void lstm_scan(
    const float* __restrict__ x,    const float* __restrict__ wih0,
    const float* __restrict__ bih0, const float* __restrict__ bhh0,
    const float* __restrict__ bih1, const float* __restrict__ bhh1,
    const float* __restrict__ bih2, const float* __restrict__ bhh2,
    const _Float16* __restrict__ wp, _Float16* __restrict__ hsave,
    const float* __restrict__ g1w, float* __restrict__ xl1)
{
  __shared__ __align__(16) _Float16 hseq[TCH*2048];  // 128 KB inter-layer h ring
  __shared__ __align__(16) _Float16 hb[2*2048];      // 8 KB ping-pong h (fp16)
  __shared__ __align__(16) _Float16 xall[TT*SBLK];   // 2 KB

  const int tid  = threadIdx.x;
  const int lane = tid & 63, wv = tid >> 6;
  const int u    = 16*wv + (lane & 15);
  const int s0   = blockIdx.x * SBLK;
  const int b    = s0 >> 9, n0 = s0 & (NN-1);

  for (int i = tid; i < TT*SBLK; i += NTHR)
    xall[i] = (_Float16)x[(b*TT + (i>>4))*NN + n0 + (i&15)];

  float4 b0, b1, b2, w0g;
  #pragma unroll
  for (int g=0; g<4; g++){
    b0[g]  = bih0[g*HID+u] + bhh0[g*HID+u];
    b1[g]  = bih1[g*HID+u] + bhh1[g*HID+u];
    b2[g]  = bih2[g*HID+u] + bhh2[g*HID+u];
    w0g[g] = wih0[g*HID+u];
  }

  float cs0[4]={0,0,0,0}, cs1[4]={0,0,0,0}, cs2[4]={0,0,0,0};
  float hlast[4]={0,0,0,0};

  #pragma unroll 1
  for (int ch=0; ch<NCH; ++ch){
    scan_phase<0>(ch, wp, hsave, hseq, hb, xall, b0, w0g, cs0, hlast);
    scan_phase<1>(ch, wp, hsave, hseq, hb, xall, b1, w0g, cs1, hlast);
    scan_phase<2>(ch, wp, hsave, hseq, hb, xall, b2, w0g, cs2, hlast);
  }

  // ---- fused xl1 = h_last @ g1w^T (feats never materialized) ----
  float* hf = (float*)hb;              // 8KB: [16][128] fp32 h_last tile
  #pragma unroll
  for (int r=0;r<4;r++) hf[(4*(lane>>4)+r)*HID + u] = hlast[r];
  __syncthreads();

  const int o  = tid & 127, rb = tid >> 7;       // 4 rows per thread
  const float4* gw = (const float4*)(g1w + o*HID);
  float accv[4] = {0.f,0.f,0.f,0.f};
  #pragma unroll 8
  for (int k4=0;k4<32;k4++){
    float4 w = gw[k4];
    #pragma unroll
    for (int i=0;i<4;i++){
      float4 hv = *(const float4*)(hf + (rb*4+i)*HID + k4*4);
      accv[i] += hv.x*w.x + hv.y*w.y + hv.z*w.z + hv.w*w.w;
    }
  }
  #pragma unroll
  for (int i=0;i<4;i++)
    xl1[(s0 + rb*4 + i)*HID + o] = accv[i];
}

// ---------------------------------------------------------------------------
// Graph-prep kernels
// ---------------------------------------------------------------------------
__global__ void deg_init(float* deg, float* out, const float* __restrict__ clb){
  int i = blockIdx.x*256 + threadIdx.x;
  if (i < NN) deg[i] = 1.0f;             // self-loop
  if (i < NB) out[i] = clb[0];           // seed classifier bias (atomics add)
}
__global__ void deg_edges(const int* __restrict__ ei, float* deg){
  int e = blockIdx.x*256 + threadIdx.x;
  if (e < EE) atomicAdd(&deg[ei[EE+e]], 1.0f);
}
__global__ void build_A(const int* __restrict__ ei, const float* __restrict__ deg,
                        float* __restrict__ A){
  int e = blockIdx.x*256 + threadIdx.x;
  if (e < EE){
    int s = ei[e], d = ei[EE+e];
    atomicAdd(&A[d*NN+s], rsqrtf(deg[s])*rsqrtf(deg[d]));
  } else if (e < EE+NN){
    int n = e - EE;
    atomicAdd(&A[n*NN+n], 1.0f/deg[n]);
  }
}

// ---------------------------------------------------------------------------
// agg1 + gemm64 fused: block computes Y[b, n0..n0+15, 0:128] = A@xl1 rows,
// stashes in LDS, then xl2[rows][0:64] = relu(Y+g1b) @ g2w^T directly.
// agg1 is never materialized.
// ---------------------------------------------------------------------------
__global__ __launch_bounds__(512) void gcn_agg_g2(const float* __restrict__ A,
    const float* __restrict__ X, const float* __restrict__ g1b,
    const float* __restrict__ g2w, float* __restrict__ xl2)
{
  __shared__ __align__(16) float As[16*NN];   // 32 KB
  __shared__ __align__(16) float sh[16*HID];  // 8 KB agg rows
  const int b = blockIdx.x, n0 = blockIdx.y*16;
  const int tid = threadIdx.x;
  const int f4 = tid & 31, nr = tid >> 5;
  for (int i = tid; i < 16*NN; i += 512) As[i] = A[n0*NN + i];
  __syncthreads();
  const float* Xb = X + b*NN*HID + f4*4;
  const float* Ar = As + nr*NN;
  float4 s = {0,0,0,0};
  #pragma unroll 4
  for (int m=0;m<NN;m++){
    float a = Ar[m];
    float4 xv = *(const float4*)(Xb + m*HID);
    s.x += a*xv.x; s.y += a*xv.y; s.z += a*xv.z; s.w += a*xv.w;
  }
  *(float4*)(sh + nr*HID + f4*4) = s;
  __syncthreads();

  const int o2 = tid & 63, r0 = (tid >> 6)*2;  // 2 rows per thread
  const float4* w2 = (const float4*)(g2w + o2*HID);
  const float4* bb = (const float4*)g1b;
  float a0 = 0.f, a1 = 0.f;
  #pragma unroll 8
  for (int k4=0;k4<32;k4++){
    float4 w = w2[k4], bv = bb[k4];
    float4 h0 = *(const float4*)(sh + r0*HID + k4*4);
    float4 h1 = *(const float4*)(sh + (r0+1)*HID + k4*4);
    a0 += fmaxf(h0.x+bv.x,0.f)*w.x + fmaxf(h0.y+bv.y,0.f)*w.y
        + fmaxf(h0.z+bv.z,0.f)*w.z + fmaxf(h0.w+bv.w,0.f)*w.w;
    a1 += fmaxf(h1.x+bv.x,0.f)*w.x + fmaxf(h1.y+bv.y,0.f)*w.y
        + fmaxf(h1.z+bv.z,0.f)*w.z + fmaxf(h1.w+bv.w,0.f)*w.w;
  }
  xl2[(b*NN + n0 + r0)*64 + o2]   = a0;
  xl2[(b*NN + n0 + r0+1)*64 + o2] = a1;
}

// agg2 + finalize fused (R18-verified): relu(A@xl2+b2).clw block-reduced,
// atomicAdd into out[b] (out pre-seeded with clb).
__global__ __launch_bounds__(256) void gcn_agg_fin(const float* __restrict__ A,
    const float* __restrict__ X, const float* __restrict__ b2,
    const float* __restrict__ clw, float* __restrict__ out)
{
  const int KOUT = 64, F4 = 16, TN = 16;
  __shared__ __align__(16) float As[TN*NN];
  __shared__ float red[256];
  const int b = blockIdx.x, n0 = blockIdx.y*TN;
  const int tid = threadIdx.x;
  const int f4 = tid & (F4-1), nr = tid / F4;
  for (int i = tid; i < TN*NN; i += TN*F4) As[i] = A[n0*NN + i];
  __syncthreads();
  const float* Xb = X + b*NN*KOUT + f4*4;
  const float* Ar = As + nr*NN;
  float4 s = {0,0,0,0};
  #pragma unroll 4
  for (int m=0;m<NN;m++){
    float a = Ar[m];
    float4 xv = *(const float4*)(Xb + m*KOUT);
    s.x += a*xv.x; s.y += a*xv.y; s.z += a*xv.z; s.w += a*xv.w;
  }
  const float4 bv = *(const float4*)(b2 + f4*4);
  const float4 cv = *(const float4*)(clw + f4*4);
  float p = fmaxf(s.x+bv.x,0.f)*cv.x + fmaxf(s.y+bv.y,0.f)*cv.y
          + fmaxf(s.z+bv.z,0.f)*cv.z + fmaxf(s.w+bv.w,0.f)*cv.w;
  red[tid] = p; __syncthreads();
  for (int sfd=128; sfd>0; sfd>>=1){
    if (tid < sfd) red[tid] += red[tid+sfd];
    __syncthreads();
  }
  if (tid==0) atomicAdd(&out[b], red[0]*(1.0f/NN));
}

extern "C" void kernel_launch(void* const* d_in, const int* in_sizes, int n_in,
                              void* d_out, int out_size, void* d_ws, size_t ws_size,
                              hipStream_t stream)
{
  const float* x    = (const float*)d_in[0];
  const int*   ei   = (const int*)  d_in[1];
  const float* wih0 = (const float*)d_in[2];
  const float* whh0 = (const float*)d_in[3];
  const float* bih0 = (const float*)d_in[4];
  const float* bhh0 = (const float*)d_in[5];
  const float* wih1 = (const float*)d_in[6];
  const float* whh1 = (const float*)d_in[7];
  const float* bih1 = (const float*)d_in[8];
  const float* bhh1 = (const float*)d_in[9];
  const float* wih2 = (const float*)d_in[10];
  const float* whh2 = (const float*)d_in[11];
  const float* bih2 = (const float*)d_in[12];
  const float* bhh2 = (const float*)d_in[13];
  const float* g1w  = (const float*)d_in[14];
  const float* g1b  = (const float*)d_in[15];
  const float* g2w  = (const float*)d_in[16];
  const float* g2b  = (const float*)d_in[17];
  const float* clw  = (const float*)d_in[18];
  const float* clb  = (const float*)d_in[19];
  float* out = (float*)d_out;

  char* ws = (char*)d_ws;
  float* xl1   = (float*)(ws + 2097152);       // [8,512,128] 2 MB (post-lstm)
  float* xl2   = (float*)(ws + 6291456);       // [8,512,64]  1 MB (post-lstm)
  float* A     = (float*)(ws + 8388608);       // [512,512]   1 MB
  float* deg   = (float*)(ws + 9437184);       // [512]

  // Overlays (safe by stream order + verified self-alias layout):
  //  - hsave [3][256] stride 8KB = 6MB at ws+0 (region dead during scan;
  //    block i's xl1 rows == hsave[1][i], written only after its own
  //    restore — self-block alias, R16/R18-verified pattern).
  //  - wp (640KB fp16 weight planes) in the xl2 slot (consumed by lstm_scan
  //    strictly before gcn_agg_g2 writes xl2).
  _Float16* hsaveW = (_Float16*)(ws);
  _Float16* wpW    = (_Float16*)(ws + 6291456);

  prep_w<<<(5*G4*HID)/256, 256, 0, stream>>>(whh0, wih1, whh1, wih2, whh2, wpW);

  hipMemsetAsync(A, 0, NN*NN*sizeof(float), stream);
  deg_init <<<2, 256, 0, stream>>>(deg, out, clb);
  deg_edges<<<EE/256, 256, 0, stream>>>(ei, deg);
  build_A  <<<(EE+NN+255)/256, 256, 0, stream>>>(ei, deg, A);

  lstm_scan<<<256, NTHR, 0, stream>>>(x, wih0, bih0, bhh0,
      bih1, bhh1, bih2, bhh2, wpW, hsaveW, g1w, xl1);

  gcn_agg_g2 <<<dim3(NB, NN/16), 512, 0, stream>>>(A, xl1, g1b, g2w, xl2);
  gcn_agg_fin<<<dim3(NB, NN/16), 256, 0, stream>>>(A, xl2, g2b, clw, out);
}